// Round 1
// baseline (336.813 us; speedup 1.0000x reference)
//
#include <hip/hip_runtime.h>

#define W_ 320
#define H_ 96
#define B_ 4
#define C_ 256
#define CS (H_ * W_)          // 30720
#define MT_ 160               // M per block (queries)
#define PITCHD 17             // dwords per LDS tile row (odd -> bank-spread)
#define PITCH 34              // shorts per LDS tile row
#define PITCHC 321            // corr chunk row pitch (shorts)
#define ABUF (MT_ * PITCH)    // 5440 shorts (2720 dwords)
#define BBUF (W_ * PITCH)     // 10880 shorts
#define TBUF (ABUF + BBUF)    // 16320 shorts per K-step buffer

typedef __attribute__((ext_vector_type(8))) short short8;
typedef __attribute__((ext_vector_type(4))) float f32x4;

static __device__ __forceinline__ unsigned f2bf(float f) {
  unsigned u = __builtin_bit_cast(unsigned, f);
  return (u + 0x7FFFu + ((u >> 16) & 1u)) >> 16;   // RNE fp32 -> bf16
}
// hardware packed RNE convert: lo = a, hi = b (identical bits to f2bf pair)
static __device__ __forceinline__ unsigned pk(float a, float b) {
  unsigned r;
  asm("v_cvt_pk_bf16_f32 %0, %1, %2" : "=v"(r) : "v"(a), "v"(b));
  return r;
}
static __device__ __forceinline__ float bf2f(unsigned short h) {
  return __builtin_bit_cast(float, (unsigned)h << 16);
}
// Barrier that does NOT drain vmcnt: LDS visibility via lgkmcnt(0), but
// prefetch global loads stay in flight across it (plain __syncthreads would
// emit s_waitcnt vmcnt(0) and collapse the 2-deep pipeline).
static __device__ __forceinline__ void bar_keepvm() {
  asm volatile("s_waitcnt lgkmcnt(0)\n\ts_barrier" ::: "memory");
}

union Frag { short8 s; uint4 u; };

// One block = one (b,hh, half-row): M=160 queries x N=320 cols x K=256 channels.
// fp32 read-direct, bf16 LDS tiles (row-permuted layout), double-buffered,
// 2-deep register prefetch with counted vmcnt (never drains in the K-loop).
__global__ __launch_bounds__(512, 2) void corr_row(
    const float* __restrict__ fmap1, const float* __restrict__ fmap2,
    const float* __restrict__ cents, float* __restrict__ out)
{
  __shared__ __align__(16) unsigned short smem[2 * TBUF];   // 65280 B
  unsigned short* Csh = smem;                               // epilogue chunk: 80*321 shorts

  const int tid  = threadIdx.x;
  const int lane = tid & 63;
  const int wv   = tid >> 6;      // 0..7
  const int mw   = wv >> 2;       // 0..1  (M half: 80 rows)
  const int nw   = wv & 3;        // 0..3  (N quarter: 80 cols)
  const int m    = lane & 15;
  const int quad = lane >> 4;

  // XCD-paired decode: both halves of row r share blockIdx%8 (L2 locality)
  const int i    = blockIdx.x;                 // 0..767
  const int r    = ((i >> 4) << 3) | (i & 7);  // 0..383 == b*H_+hh
  const int half = (i >> 3) & 1;
  const int b    = r / H_;
  const int hh   = r % H_;
  const int q0   = half * MT_;

  const float* Abase = fmap1 + ((size_t)b * C_ * H_ + hh) * W_ + q0; // + c*CS + v
  const float* Bbase = fmap2 + ((size_t)b * C_ * H_ + hh) * W_;      // + c*CS + v

  // ---- per-thread staging slots (4): item id = tid + 512*p, 1920 items/step ----
  // A items (it<640):  c2 = it/40, k = it%40 (v0 = 4k)   (A: 160 rows)
  // B items (it>=640): c2 = ib/80, k = ib%80 (v0 = 4k)   (B: 320 rows)
  // LDS physical row permutation: p(v) = (v&3)*R4 + (v>>2), R4 = rows/4.
  //   -> thread's 4 row-writes stride R4*17 dwords; lane-to-lane stride is
  //      17 dwords (odd) -> conflict-free ds_writes (was ~5-way).
  //   -> fragment read row v maps to p = (m&3)*R4 + (tilebase>>2) + (m>>2).
  const float* sp[4];
  int dsti[4];        // LDS dword index of (rr=0 row, c2) within its tile
  bool act[4];
#pragma unroll
  for (int p = 0; p < 4; ++p) {
    int it = tid + 512 * p;
    act[p] = (it < 1920);
    bool isA = (it < 640);
    int c2, k;
    if (isA) { c2 = it / 40; k = it % 40; }
    else     { int ib = it - 640; c2 = ib / 80; k = ib % 80; }
    if (!act[p]) { c2 = 0; k = 0; }
    sp[p]   = (isA ? Abase : Bbase) + (size_t)(2 * c2) * CS + 4 * k;
    dsti[p] = k * PITCHD + c2 + (isA ? 0 : ABUF / 2);
  }
  // p==0 is pure A, p>=2 pure B (compile-time strides); p==1 is mixed.
  const int st1 = (tid < 128) ? 40 * PITCHD : 80 * PITCHD;

  f32x4 acc[5][5] = {};
  Frag fa[5];

  float4 g0[4][2], g1[4][2];

  auto issue = [&](int s, float4 (*g)[2]) {
#pragma unroll
    for (int p = 0; p < 4; ++p)
      if (act[p]) {
        const float* q = sp[p] + (size_t)(s * 32) * CS;
        g[p][0] = *(const float4*)q;
        g[p][1] = *(const float4*)(q + CS);
      }
  };
  auto stage = [&](int s, float4 (*g)[2]) {
    unsigned* buf = (unsigned*)(smem + (s & 1) * TBUF);
#pragma unroll
    for (int p = 0; p < 4; ++p)
      if (act[p]) {
        unsigned* d = buf + dsti[p];
        const int st = (p == 0) ? 40 * PITCHD : (p >= 2 ? 80 * PITCHD : st1);
        d[0]      = pk(g[p][0].x, g[p][1].x);
        d[st]     = pk(g[p][0].y, g[p][1].y);
        d[2 * st] = pk(g[p][0].z, g[p][1].z);
        d[3 * st] = pk(g[p][0].w, g[p][1].w);
      }
  };

  // permuted physical row bases for fragment reads (mt/nt add 4 per tile step)
  const int pbA = (m & 3) * 40 + mw * 20 + (m >> 2);
  const int pbB = (m & 3) * 80 + nw * 20 + (m >> 2);

  auto fragmfma = [&](int s) {
    const unsigned* buf = (const unsigned*)(smem + (s & 1) * TBUF);
#pragma unroll
    for (int mt = 0; mt < 5; ++mt) {
      const unsigned* pa = buf + (pbA + mt * 4) * PITCHD + quad * 4;
      fa[mt].u.x = pa[0]; fa[mt].u.y = pa[1]; fa[mt].u.z = pa[2]; fa[mt].u.w = pa[3];
    }
#pragma unroll
    for (int nt = 0; nt < 5; ++nt) {
      const unsigned* pb = buf + (ABUF / 2) + (pbB + nt * 4) * PITCHD + quad * 4;
      Frag fb;
      fb.u.x = pb[0]; fb.u.y = pb[1]; fb.u.z = pb[2]; fb.u.w = pb[3];
#pragma unroll
      for (int mt = 0; mt < 5; ++mt)
        acc[mt][nt] = __builtin_amdgcn_mfma_f32_16x16x32_bf16(
            fa[mt].s, fb.s, acc[mt][nt], 0, 0, 0);
    }
  };

  // ---- K-loop: 2-deep prefetch, one raw barrier per K-step ----
  // At stage(hs): g(hs) [issued hs-2] and g(hs+1) [issued hs-1] outstanding
  //   -> compiler waits vmcnt(8); never drains to 0 until the last step.
  // stage(hs) writes buf[hs&1], last read at fragmfma(hs-2), which all waves
  //   finished before bar(hs-1) -> race-free with one barrier per step.
  issue(0, g0);
  issue(1, g1);
#pragma unroll
  for (int hs = 0; hs < 8; ++hs) {
    if (hs & 1) {
      stage(hs, g1);
      bar_keepvm();
      if (hs < 6) issue(hs + 2, g1);   // reuse freed buffer, 2 steps ahead
    } else {
      stage(hs, g0);
      bar_keepvm();
      if (hs < 6) issue(hs + 2, g0);
    }
    fragmfma(hs);
  }

  // ---- epilogue: two 80-query chunks through Csh (unions with buffers) ----
#pragma unroll 1
  for (int chunk = 0; chunk < 2; ++chunk) {
    __syncthreads();   // K-loop frag reads done / chunk0 sampling done
    if (mw == chunk) {
      // C/D layout: col = lane&15, row = quad*4 + reg
#pragma unroll
      for (int mt = 0; mt < 5; ++mt)
#pragma unroll
        for (int nt = 0; nt < 5; ++nt)
#pragma unroll
          for (int rr = 0; rr < 4; ++rr)
            Csh[(mt * 16 + quad * 4 + rr) * PITCHC + nw * 80 + nt * 16 + m] =
                (unsigned short)f2bf(acc[mt][nt][rr] * 0.0625f);
    }
    __syncthreads();
    if (tid < 320) {
      const int l = tid / 80;          // level
      const int q = tid % 80;          // query within chunk
      const int qg = q0 + chunk * 80 + q;
      const int Wl  = W_ >> l;
      const int mul = 1 << l;
      const float invm = 1.0f / (float)mul;
      const float cent = cents[(b * H_ + hh) * W_ + qg];
      const float cl = cent * invm;    // exact pow2 scaling == iterated /2
      const unsigned short* crow = Csh + q * PITCHC;
      float* op = out + ((size_t)(b * 36 + l * 9) * H_ + hh) * W_ + qg;
#pragma unroll
      for (int j = 0; j < 9; ++j) {
        float x  = cl + (float)(j - 4);
        float x0 = floorf(x);
        float t  = x - x0;
        int i0 = (int)x0;
        float v0 = 0.0f, v1 = 0.0f;
        if (i0 >= 0 && i0 < Wl) {
          float s2 = 0.0f;
          for (int d = 0; d < mul; ++d) s2 += bf2f(crow[i0 * mul + d]);
          v0 = s2 * invm;
        }
        int i1 = i0 + 1;
        if (i1 >= 0 && i1 < Wl) {
          float s2 = 0.0f;
          for (int d = 0; d < mul; ++d) s2 += bf2f(crow[i1 * mul + d]);
          v1 = s2 * invm;
        }
        op[(size_t)j * H_ * W_] = v0 * (1.0f - t) + v1 * t;
      }
    }
  }
}

extern "C" void kernel_launch(void* const* d_in, const int* in_sizes, int n_in,
                              void* d_out, int out_size, void* d_ws, size_t ws_size,
                              hipStream_t stream) {
  const float* fmap1 = (const float*)d_in[0];
  const float* fmap2 = (const float*)d_in[1];
  const float* cents = (const float*)d_in[2];
  float* out = (float*)d_out;
  corr_row<<<dim3(768), 512, 0, stream>>>(fmap1, fmap2, cents, out);
}

// Round 2
// 293.677 us; speedup vs baseline: 1.1469x; 1.1469x over previous
//
#include <hip/hip_runtime.h>

#define W_ 320
#define H_ 96
#define B_ 4
#define C_ 256
#define CS (H_ * W_)          // 30720
#define MT_ 64                // M per block (queries)  -> acc[2][5] = 40 regs/wave
#define PITCHD 17             // dwords per LDS tile row (odd -> bank-spread)
#define GA 24                 // A physical row-group stride: 24*17 % 32 == 24 (order-4)
#define GB 88                 // B physical row-group stride: 88*17 % 32 == 24 (order-4)
#define ADW (( (3*GA) + 16) * PITCHD)   // A region: 88 rows * 17 = 1496 dwords
#define BDW (( (3*GB) + 80) * PITCHD)   // B region: 344 rows * 17 = 5848 dwords
#define TBUFD (ADW + BDW)               // 7344 dwords per K-step buffer (29376 B)
#define PITCHC 321            // corr chunk row pitch (shorts)

typedef __attribute__((ext_vector_type(8))) short short8;
typedef __attribute__((ext_vector_type(4))) float f32x4;

static __device__ __forceinline__ unsigned f2bf(float f) {
  unsigned u = __builtin_bit_cast(unsigned, f);
  return (u + 0x7FFFu + ((u >> 16) & 1u)) >> 16;   // RNE fp32 -> bf16
}
// hardware packed RNE convert: lo = a, hi = b (identical bits to f2bf pair)
static __device__ __forceinline__ unsigned pk(float a, float b) {
  unsigned r;
  asm("v_cvt_pk_bf16_f32 %0, %1, %2" : "=v"(r) : "v"(a), "v"(b));
  return r;
}
static __device__ __forceinline__ float bf2f(unsigned short h) {
  return __builtin_bit_cast(float, (unsigned)h << 16);
}
// Barrier without vmcnt drain: LDS visibility via lgkmcnt(0); prefetch global
// loads stay in flight across it.
static __device__ __forceinline__ void bar_keepvm() {
  asm volatile("s_waitcnt lgkmcnt(0)\n\ts_barrier" ::: "memory");
}

union Frag { short8 s; uint4 u; };

// One block = (b,hh, fifth-of-row): M=64 queries x N=320 cols x K=256 channels.
// Wave tile 32x80 -> acc = 40 regs. Total ~100 regs/wave + 58.8 KB LDS
// -> 2 blocks/CU (4 waves/SIMD): independent barrier domains hide load latency.
__global__ __launch_bounds__(512, 4) void corr_row(
    const float* __restrict__ fmap1, const float* __restrict__ fmap2,
    const float* __restrict__ cents, float* __restrict__ out)
{
  __shared__ __align__(16) unsigned short smem[2 * 2 * TBUFD];  // 58752 B
  unsigned short* Csh = smem;   // epilogue: 64*321 = 20544 shorts (fits)

  const int tid  = threadIdx.x;
  const int lane = tid & 63;
  const int wv   = tid >> 6;      // 0..7
  const int mw   = wv >> 2;       // 0..1  (M half: 32 rows)
  const int nw   = wv & 3;        // 0..3  (N quarter: 80 cols)
  const int m    = lane & 15;
  const int quad = lane >> 4;

  // XCD-pinned decode: the 5 blocks sharing a (b,hh) row all have the same
  // blockIdx%8 and adjacent per-XCD dispatch slots -> fmap2 row (327 KB)
  // served from one XCD's L2 despite 5x staging redundancy.
  const int i   = blockIdx.x;          // 0..1919
  const int xcd = i & 7;
  const int t   = i >> 3;              // 0..239
  const int r   = (t / 5) * 8 + xcd;   // 0..383 == b*H_+hh
  const int mb  = t % 5;
  const int b   = r / H_;
  const int hh  = r % H_;
  const int q0  = mb * MT_;

  const float* Abase = fmap1 + ((size_t)b * C_ * H_ + hh) * W_ + q0; // + c*CS + v
  const float* Bbase = fmap2 + ((size_t)b * C_ * H_ + hh) * W_;      // + c*CS + v

  // ---- per-thread staging slots (3): item id = tid + 512*p, 1536 items/step ----
  // A items (it<256):   c2 = it/16, k = it%16  (A: 64 rows, 16 row-groups)
  // B items (it>=256):  c2 = ib/80, k = ib%80  (B: 320 rows, 80 row-groups)
  // LDS physical row permutation: p(4k+j) = j*G + k  (G: GA=24 / GB=88).
  //   writes: lane-to-lane stride 17 dwords (odd)        -> conflict-free
  //   reads:  (m&3)*G*17 % 32 == 24 (order 4 in Z32)     -> 16 distinct banks
  const float* sp[3];
  int dsti[3];
#pragma unroll
  for (int p = 0; p < 3; ++p) {
    int it = tid + 512 * p;
    bool isA = (it < 256);
    int c2, k;
    if (isA) { c2 = it >> 4; k = it & 15; }
    else     { int ib = it - 256; c2 = ib / 80; k = ib % 80; }
    sp[p]   = (isA ? Abase : Bbase) + (size_t)(2 * c2) * CS + 4 * k;
    dsti[p] = k * PITCHD + c2 + (isA ? 0 : ADW);
  }
  // j-stride (physical rows per +1 of j, times pitch): A 24*17=408, B 88*17=1496
  const int jst0 = (tid < 256) ? GA * PITCHD : GB * PITCHD;   // wave-uniform

  f32x4 acc[2][5] = {};
  Frag fa[2];
  float4 g[3][2];

  auto issue = [&](int s) {
#pragma unroll
    for (int p = 0; p < 3; ++p) {
      const float* q = sp[p] + (size_t)(s * 32) * CS;
      g[p][0] = *(const float4*)q;
      g[p][1] = *(const float4*)(q + CS);
    }
  };
  auto stage = [&](int s) {
    unsigned* buf = (unsigned*)smem + (s & 1) * TBUFD;
#pragma unroll
    for (int p = 0; p < 3; ++p) {
      unsigned* d = buf + dsti[p];
      const int st = (p == 0) ? jst0 : GB * PITCHD;
      d[0]      = pk(g[p][0].x, g[p][1].x);
      d[st]     = pk(g[p][0].y, g[p][1].y);
      d[2 * st] = pk(g[p][0].z, g[p][1].z);
      d[3 * st] = pk(g[p][0].w, g[p][1].w);
    }
  };

  // permuted physical-row read bases (mt/nt add 4 logical row-groups per step)
  const int pbA = ((m & 3) * GA + mw * 8 + (m >> 2)) * PITCHD + quad * 4;
  const int pbB = ADW + ((m & 3) * GB + nw * 20 + (m >> 2)) * PITCHD + quad * 4;

  auto fragmfma = [&](int s) {
    const unsigned* buf = (const unsigned*)smem + (s & 1) * TBUFD;
#pragma unroll
    for (int mt = 0; mt < 2; ++mt) {
      const unsigned* pa = buf + pbA + mt * 4 * PITCHD;
      fa[mt].u.x = pa[0]; fa[mt].u.y = pa[1]; fa[mt].u.z = pa[2]; fa[mt].u.w = pa[3];
    }
#pragma unroll
    for (int nt = 0; nt < 5; ++nt) {
      const unsigned* pb = buf + pbB + nt * 4 * PITCHD;
      Frag fb;
      fb.u.x = pb[0]; fb.u.y = pb[1]; fb.u.z = pb[2]; fb.u.w = pb[3];
#pragma unroll
      for (int mt = 0; mt < 2; ++mt)
        acc[mt][nt] = __builtin_amdgcn_mfma_f32_16x16x32_bf16(
            fa[mt].s, fb.s, acc[mt][nt], 0, 0, 0);
    }
  };

  // ---- K-loop: 1-deep register prefetch, one raw barrier per half-step.
  // issue(hs+1) right after the barrier -> loads in flight across fragmfma(hs);
  // stage(hs) writes buf[hs&1], last read by fragmfma(hs-2) before bar(hs-1).
  // Cross-block TLP (2 blocks/CU) covers the residual latency.
  issue(0);
#pragma unroll
  for (int hs = 0; hs < 8; ++hs) {
    stage(hs);
    bar_keepvm();
    if (hs < 7) issue(hs + 1);
    fragmfma(hs);
  }

  // ---- epilogue: single 64-query chunk through Csh (unions with buffers) ----
  __syncthreads();   // K-loop frag reads done
  // C/D layout: col = lane&15, row = quad*4 + reg
#pragma unroll
  for (int mt = 0; mt < 2; ++mt)
#pragma unroll
    for (int nt = 0; nt < 5; ++nt)
#pragma unroll
      for (int rr = 0; rr < 4; ++rr)
        Csh[(mw * 32 + mt * 16 + quad * 4 + rr) * PITCHC + nw * 80 + nt * 16 + m] =
            (unsigned short)f2bf(acc[mt][nt][rr] * 0.0625f);
  __syncthreads();
  if (tid < 256) {
    const int l = tid >> 6;          // level
    const int q = tid & 63;          // query within block
    const int qg = q0 + q;
    const int Wl  = W_ >> l;
    const int mul = 1 << l;
    const float invm = 1.0f / (float)mul;
    const float cent = cents[(b * H_ + hh) * W_ + qg];
    const float cl = cent * invm;    // exact pow2 scaling == iterated /2
    const unsigned short* crow = Csh + q * PITCHC;
    float* op = out + ((size_t)(b * 36 + l * 9) * H_ + hh) * W_ + qg;
#pragma unroll
    for (int j = 0; j < 9; ++j) {
      float x  = cl + (float)(j - 4);
      float x0 = floorf(x);
      float t  = x - x0;
      int i0 = (int)x0;
      float v0 = 0.0f, v1 = 0.0f;
      if (i0 >= 0 && i0 < Wl) {
        float s2 = 0.0f;
        for (int d = 0; d < mul; ++d) s2 += bf2f(crow[i0 * mul + d]);
        v0 = s2 * invm;
      }
      int i1 = i0 + 1;
      if (i1 >= 0 && i1 < Wl) {
        float s2 = 0.0f;
        for (int d = 0; d < mul; ++d) s2 += bf2f(crow[i1 * mul + d]);
        v1 = s2 * invm;
      }
      op[(size_t)j * H_ * W_] = v0 * (1.0f - t) + v1 * t;
    }
  }
}

extern "C" void kernel_launch(void* const* d_in, const int* in_sizes, int n_in,
                              void* d_out, int out_size, void* d_ws, size_t ws_size,
                              hipStream_t stream) {
  const float* fmap1 = (const float*)d_in[0];
  const float* fmap2 = (const float*)d_in[1];
  const float* cents = (const float*)d_in[2];
  float* out = (float*)d_out;
  corr_row<<<dim3(1920), 512, 0, stream>>>(fmap1, fmap2, cents, out);
}